// Round 1
// baseline (3594.662 us; speedup 1.0000x reference)
//
#include <hip/hip_runtime.h>
#include <cstdint>
#include <cstddef>

#define NODE 64
#define EDGEF 32
#define UPF 160   // 2*NODE + EDGEF
#define RD 256
#define UT_STRIDE 162  // 160 padded to keep b64 LDS reads 2-way-conflict-free

__device__ __forceinline__ float eluf(float x) { return x > 0.f ? x : expm1f(x); }

// ---------------------------------------------------------------------------
// Edge FFN (depth-invariant) + weighted scatter into aggrE[N,32]
// thread per edge; E_W staged in LDS (broadcast reads)
__global__ void k_mij_aggr(const float* __restrict__ ea, const int* __restrict__ dst,
                           const float* __restrict__ wb, const float* __restrict__ EW,
                           const float* __restrict__ Eb, float* aggrE, int E) {
    __shared__ float ew_s[EDGEF * EDGEF];
    __shared__ float eb_s[EDGEF];
    int tid = threadIdx.x;
    for (int i = tid; i < EDGEF * EDGEF; i += 256) ew_s[i] = EW[i];
    if (tid < EDGEF) eb_s[tid] = Eb[tid];
    __syncthreads();
    int e = blockIdx.x * 256 + tid;
    if (e >= E) return;
    float a[EDGEF];
    const float4* row = (const float4*)(ea + (size_t)e * EDGEF);
#pragma unroll
    for (int q = 0; q < 8; ++q) {
        float4 v = row[q];
        a[4*q] = v.x; a[4*q+1] = v.y; a[4*q+2] = v.z; a[4*q+3] = v.w;
    }
    float m[EDGEF];
#pragma unroll
    for (int j = 0; j < EDGEF; ++j) m[j] = eb_s[j];
#pragma unroll
    for (int k = 0; k < EDGEF; ++k) {
        float ak = a[k];
#pragma unroll
        for (int j = 0; j < EDGEF; ++j) m[j] = fmaf(ak, ew_s[k*EDGEF + j], m[j]);
    }
    float w = wb[e];
    float* dp = aggrE + (size_t)dst[e] * EDGEF;
#pragma unroll
    for (int j = 0; j < EDGEF; ++j) atomicAdd(&dp[j], w * fmaxf(m[j], 0.f));
}

// ---------------------------------------------------------------------------
// CSR build
__global__ void k_count(const int* __restrict__ dst, int* cnt, int E) {
    int e = blockIdx.x * 256 + threadIdx.x;
    if (e < E) atomicAdd(&cnt[dst[e]], 1);
}

__global__ void k_scanA(const int* __restrict__ cnt, int* starts, int* bsum, int N) {
    __shared__ int sh[256];
    int t = threadIdx.x;
    int base = blockIdx.x * 1024 + t * 4;
    int v0 = 0, v1 = 0, v2 = 0, v3 = 0;
    if (base + 0 < N) v0 = cnt[base + 0];
    if (base + 1 < N) v1 = cnt[base + 1];
    if (base + 2 < N) v2 = cnt[base + 2];
    if (base + 3 < N) v3 = cnt[base + 3];
    int tot = v0 + v1 + v2 + v3;
    sh[t] = tot;
    __syncthreads();
    for (int off = 1; off < 256; off <<= 1) {
        int add = (t >= off) ? sh[t - off] : 0;
        __syncthreads();
        sh[t] += add;
        __syncthreads();
    }
    int excl = sh[t] - tot;
    if (base + 0 < N) starts[base + 0] = excl;
    if (base + 1 < N) starts[base + 1] = excl + v0;
    if (base + 2 < N) starts[base + 2] = excl + v0 + v1;
    if (base + 3 < N) starts[base + 3] = excl + v0 + v1 + v2;
    if (t == 255) bsum[blockIdx.x] = sh[255];
}

__global__ void k_scanB(const int* __restrict__ bsum, int* boff, int nb, int* starts, int N) {
    if (threadIdx.x == 0 && blockIdx.x == 0) {
        int run = 0;
        for (int b = 0; b < nb; ++b) { boff[b] = run; run += bsum[b]; }
        starts[N] = run;
    }
}

__global__ void k_scanC(const int* __restrict__ boff, int* starts, int* cursor, int N) {
    int i = blockIdx.x * 256 + threadIdx.x;
    if (i < N) {
        int v = starts[i] + boff[i >> 10];
        starts[i] = v;
        cursor[i] = v;
    }
}

__global__ void k_fill(const int* __restrict__ src, const int* __restrict__ dst,
                       const float* __restrict__ wb, int* cursor,
                       int* esrc, float* ewS, int E) {
    int e = blockIdx.x * 256 + threadIdx.x;
    if (e < E) {
        int d = dst[e];
        int pos = atomicAdd(&cursor[d], 1);
        esrc[pos] = src[e];
        ewS[pos] = wb[e];
    }
}

// ---------------------------------------------------------------------------
// Fused message-passing depth: per-node aggregation (no atomics) + elu + U-FFN
// wave per node. lane j owns channel j. V column j in VGPRs; U^T in LDS.
__global__ __launch_bounds__(256, 3) void k_node(
    const float* __restrict__ h_in, float* __restrict__ h_out,
    const int* __restrict__ starts, const int* __restrict__ esrc,
    const float* __restrict__ ewS, const float* __restrict__ aggrE,
    const float* __restrict__ VW, const float* __restrict__ Vb,
    const float* __restrict__ UW, const float* __restrict__ Ub,
    const float* __restrict__ watoms, int N) {
    __shared__ float lds_Ut[NODE * UT_STRIDE];
    __shared__ float lds_up[4 * UPF];
    int tid = threadIdx.x;
    // stage U^T: Ut[j][t] = U[t*64+j]
    for (int idx = tid; idx < UPF * NODE; idx += 256) {
        int j = idx & 63, t2 = idx >> 6;
        lds_Ut[j * UT_STRIDE + t2] = UW[idx];
    }
    int lane = tid & 63, wid = tid >> 6;
    float vcol[NODE];
#pragma unroll
    for (int k = 0; k < NODE; ++k) vcol[k] = VW[k * NODE + lane];
    float vb = Vb[lane];
    float ub = Ub[lane];
    __syncthreads();
    float* myup = lds_up + wid * UPF;
    int nwaves = gridDim.x * 4;
    for (int n = blockIdx.x * 4 + wid; n < N; n += nwaves) {
        int s0 = starts[n], s1 = starts[n + 1];
        float acc = 0.f;
        int i = s0;
        int sidxN = 0; float ewN = 0.f;
        if (i < s1) { sidxN = esrc[i]; ewN = ewS[i]; }
        for (; i < s1; ++i) {
            int sidx = __builtin_amdgcn_readfirstlane(sidxN);
            float we = ewN;
            if (i + 1 < s1) { sidxN = esrc[i + 1]; ewN = ewS[i + 1]; }
            const float* hp = h_in + (size_t)sidx * NODE;
            float dot = vb;
#pragma unroll
            for (int k = 0; k < NODE; ++k) dot = fmaf(hp[k], vcol[k], dot);
            acc = fmaf(we, fmaxf(dot, 0.f), acc);
        }
        // build up = elu([acc(64) | aggrE(32) | h_in[n](64)])
        myup[lane] = eluf(acc);
        if (lane < EDGEF) myup[NODE + lane] = eluf(aggrE[(size_t)n * EDGEF + lane]);
        myup[NODE + EDGEF + lane] = eluf(h_in[(size_t)n * NODE + lane]);
        // U-FFN: o_j = relu(sum_t up[t]*U[t][j] + Ub_j) * w_atoms[n]
        float o = ub;
#pragma unroll
        for (int t2 = 0; t2 < UPF; t2 += 2) {
            float2 u2 = *(const float2*)&myup[t2];                 // broadcast
            float2 w2 = *(const float2*)&lds_Ut[lane * UT_STRIDE + t2];
            o = fmaf(u2.x, w2.x, o);
            o = fmaf(u2.y, w2.y, o);
        }
        h_out[(size_t)n * NODE + lane] = fmaxf(o, 0.f) * watoms[n];
    }
}

// ---------------------------------------------------------------------------
__global__ void k_add4(const float4* __restrict__ a, const float4* __restrict__ b,
                       float4* __restrict__ o, int n4) {
    int i = blockIdx.x * 256 + threadIdx.x;
    if (i < n4) {
        float4 x = a[i], y = b[i];
        float4 r = { x.x + y.x, x.y + y.y, x.z + y.z, x.w + y.w };
        o[i] = r;
    }
}

// ---------------------------------------------------------------------------
// Readout GEMM y = hx @ R_W + R_b, fused column sum/sumsq for BN
__global__ __launch_bounds__(256, 2) void k_y(
    const float* __restrict__ hx, const float* __restrict__ RW,
    const float* __restrict__ Rb, float* __restrict__ y,
    float* colsum, float* colsumsq, int N) {
    __shared__ float lds_R[NODE * RD];  // 64 KB
    int tid = threadIdx.x;
    for (int i = tid; i < NODE * RD; i += 256) lds_R[i] = RW[i];
    __syncthreads();
    int lane = tid & 63, wid = tid >> 6;
    const float4* R4 = (const float4*)lds_R;
    float4 rb = ((const float4*)Rb)[lane];
    float4 sum = {0, 0, 0, 0}, sq = {0, 0, 0, 0};
    int nwaves = gridDim.x * 4;
    for (int n = blockIdx.x * 4 + wid; n < N; n += nwaves) {
        const float* hr = hx + (size_t)n * NODE;
        float4 acc = rb;
#pragma unroll
        for (int k = 0; k < NODE; ++k) {
            float hk = hr[k];                 // wave-uniform -> scalar load
            float4 r = R4[k * 64 + lane];
            acc.x = fmaf(hk, r.x, acc.x);
            acc.y = fmaf(hk, r.y, acc.y);
            acc.z = fmaf(hk, r.z, acc.z);
            acc.w = fmaf(hk, r.w, acc.w);
        }
        ((float4*)y)[(size_t)n * 64 + lane] = acc;
        sum.x += acc.x; sum.y += acc.y; sum.z += acc.z; sum.w += acc.w;
        sq.x = fmaf(acc.x, acc.x, sq.x); sq.y = fmaf(acc.y, acc.y, sq.y);
        sq.z = fmaf(acc.z, acc.z, sq.z); sq.w = fmaf(acc.w, acc.w, sq.w);
    }
    atomicAdd(&colsum[lane * 4 + 0], sum.x);
    atomicAdd(&colsum[lane * 4 + 1], sum.y);
    atomicAdd(&colsum[lane * 4 + 2], sum.z);
    atomicAdd(&colsum[lane * 4 + 3], sum.w);
    atomicAdd(&colsumsq[lane * 4 + 0], sq.x);
    atomicAdd(&colsumsq[lane * 4 + 1], sq.y);
    atomicAdd(&colsumsq[lane * 4 + 2], sq.z);
    atomicAdd(&colsumsq[lane * 4 + 3], sq.w);
}

// graph boundaries from sorted batch: gstart[g] = first n with batch[n] >= g
__global__ void k_gbounds(const int* __restrict__ batch, int* gstart, int N, int G) {
    int n = blockIdx.x * 256 + threadIdx.x;
    if (n > N) return;
    int bprev = (n == 0) ? -1 : batch[n - 1];
    int bcur = (n == N) ? G : batch[n];
    for (int g = bprev + 1; g <= bcur; ++g) gstart[g] = n;
}

// BN(normalize) + relu + segment mean. block per graph, thread per channel.
__global__ void k_out(const float* __restrict__ y, const float* __restrict__ colsum,
                      const float* __restrict__ colsumsq, const float* __restrict__ gamma,
                      const float* __restrict__ beta, const int* __restrict__ gstart,
                      float* __restrict__ out, float invN) {
    int g = blockIdx.x, c = threadIdx.x;
    float mu = colsum[c] * invN;
    float var = fmaxf(colsumsq[c] * invN - mu * mu, 0.f);
    float inv = rsqrtf(var + 1e-5f);
    float ga = gamma[c], be = beta[c];
    int a = gstart[g], b = gstart[g + 1];
    float acc = 0.f;
    for (int n = a; n < b; ++n) {
        float v = y[(size_t)n * RD + c];
        acc += fmaxf(fmaf((v - mu) * inv, ga, be), 0.f);
    }
    out[(size_t)g * RD + c] = acc / fmaxf((float)(b - a), 1.f);
}

// ---------------------------------------------------------------------------
extern "C" void kernel_launch(void* const* d_in, const int* in_sizes, int n_in,
                              void* d_out, int out_size, void* d_ws, size_t ws_size,
                              hipStream_t stream) {
    const float* x      = (const float*)d_in[0];
    const int*   ei     = (const int*)d_in[1];
    const float* eattr  = (const float*)d_in[2];
    const float* watoms = (const float*)d_in[3];
    const float* wbonds = (const float*)d_in[4];
    const int*   batch  = (const int*)d_in[5];
    const float* VW = (const float*)d_in[6];
    const float* Vb = (const float*)d_in[7];
    const float* EW = (const float*)d_in[8];
    const float* Eb = (const float*)d_in[9];
    const float* UW = (const float*)d_in[10];
    const float* Ub = (const float*)d_in[11];
    const float* RW = (const float*)d_in[12];
    const float* Rb = (const float*)d_in[13];
    const float* Rg = (const float*)d_in[14];
    const float* Rbe = (const float*)d_in[15];
    float* out = (float*)d_out;

    const int N = in_sizes[0] / NODE;
    const int E = in_sizes[4];
    const int G = out_size / RD;
    const int* src = ei;
    const int* dst = ei + E;

    char* p = (char*)d_ws;
    auto alloc = [&](size_t bytes) -> char* {
        char* r = p;
        p += (bytes + 255) & ~(size_t)255;
        return r;
    };
    float* aggrE   = (float*)alloc((size_t)N * EDGEF * 4);
    int*   cnt     = (int*)alloc((size_t)N * 4);
    int*   starts  = (int*)alloc((size_t)(N + 1) * 4);
    int*   cursor  = (int*)alloc((size_t)N * 4);
    int*   bsum    = (int*)alloc(64 * 4);
    int*   boff    = (int*)alloc(64 * 4);
    int*   esrc    = (int*)alloc((size_t)E * 4);
    float* ewS     = (float*)alloc((size_t)E * 4);
    float* h1      = (float*)alloc((size_t)N * NODE * 4);
    float* h2      = (float*)alloc((size_t)N * NODE * 4);
    float* h3      = (float*)alloc((size_t)N * NODE * 4);
    float* h4      = (float*)alloc((size_t)N * NODE * 4);
    float* tmp     = (float*)alloc((size_t)N * NODE * 4);
    float* hx      = (float*)alloc((size_t)N * NODE * 4);
    float* ybuf    = (float*)alloc((size_t)N * RD * 4);
    float* colstat = (float*)alloc((size_t)2 * RD * 4);
    int*   gstart  = (int*)alloc((size_t)(G + 1) * 4);

    hipMemsetAsync(aggrE, 0, (size_t)N * EDGEF * 4, stream);
    hipMemsetAsync(cnt, 0, (size_t)N * 4, stream);
    hipMemsetAsync(colstat, 0, (size_t)2 * RD * 4, stream);

    int eblocks = (E + 255) / 256;
    int sblocks = (N + 1023) / 1024;

    k_mij_aggr<<<eblocks, 256, 0, stream>>>(eattr, dst, wbonds, EW, Eb, aggrE, E);
    k_count<<<eblocks, 256, 0, stream>>>(dst, cnt, E);
    k_scanA<<<sblocks, 256, 0, stream>>>(cnt, starts, bsum, N);
    k_scanB<<<1, 64, 0, stream>>>(bsum, boff, sblocks, starts, N);
    k_scanC<<<(N + 255) / 256, 256, 0, stream>>>(boff, starts, cursor, N);
    k_fill<<<eblocks, 256, 0, stream>>>(src, dst, wbonds, cursor, esrc, ewS, E);

    int n4 = N * NODE / 4;
    int ablocks = (n4 + 255) / 256;

    // depth 0: h1 = mp(x)
    k_node<<<768, 256, 0, stream>>>(x, h1, starts, esrc, ewS, aggrE, VW, Vb, UW, Ub, watoms, N);
    // depth 1: h2 = mp(h1)
    k_node<<<768, 256, 0, stream>>>(h1, h2, starts, esrc, ewS, aggrE, VW, Vb, UW, Ub, watoms, N);
    // depth 2: h3 = mp(h1 + h2)
    k_add4<<<ablocks, 256, 0, stream>>>((const float4*)h1, (const float4*)h2, (float4*)tmp, n4);
    k_node<<<768, 256, 0, stream>>>(tmp, h3, starts, esrc, ewS, aggrE, VW, Vb, UW, Ub, watoms, N);
    // depth 3: h4 = mp(h2 + h3)
    k_add4<<<ablocks, 256, 0, stream>>>((const float4*)h2, (const float4*)h3, (float4*)tmp, n4);
    k_node<<<768, 256, 0, stream>>>(tmp, h4, starts, esrc, ewS, aggrE, VW, Vb, UW, Ub, watoms, N);

    // readout
    k_add4<<<ablocks, 256, 0, stream>>>((const float4*)h4, (const float4*)x, (float4*)hx, n4);
    k_y<<<512, 256, 0, stream>>>(hx, RW, Rb, ybuf, colstat, colstat + RD, N);
    k_gbounds<<<(N + 256) / 256, 256, 0, stream>>>(batch, gstart, N, G);
    k_out<<<G, RD, 0, stream>>>(ybuf, colstat, colstat + RD, Rg, Rbe, gstart, out, 1.0f / (float)N);
}

// Round 2
// 2108.622 us; speedup vs baseline: 1.7047x; 1.7047x over previous
//
#include <hip/hip_runtime.h>
#include <cstdint>
#include <cstddef>

#define NODE 64
#define EDGEF 32
#define UPF 160   // 2*NODE + EDGEF
#define RD 256
#define UT_STRIDE 162  // 160 padded: float2 reads -> 2-way bank aliasing (free)

__device__ __forceinline__ float eluf(float x) { return x > 0.f ? x : expm1f(x); }

// ---------------------------------------------------------------------------
// CSR build
__global__ void k_count(const int* __restrict__ dst, int* cnt, int E) {
    int e = blockIdx.x * 256 + threadIdx.x;
    if (e < E) atomicAdd(&cnt[dst[e]], 1);
}

__global__ void k_scanA(const int* __restrict__ cnt, int* starts, int* bsum, int N) {
    __shared__ int sh[256];
    int t = threadIdx.x;
    int base = blockIdx.x * 1024 + t * 4;
    int v0 = 0, v1 = 0, v2 = 0, v3 = 0;
    if (base + 0 < N) v0 = cnt[base + 0];
    if (base + 1 < N) v1 = cnt[base + 1];
    if (base + 2 < N) v2 = cnt[base + 2];
    if (base + 3 < N) v3 = cnt[base + 3];
    int tot = v0 + v1 + v2 + v3;
    sh[t] = tot;
    __syncthreads();
    for (int off = 1; off < 256; off <<= 1) {
        int add = (t >= off) ? sh[t - off] : 0;
        __syncthreads();
        sh[t] += add;
        __syncthreads();
    }
    int excl = sh[t] - tot;
    if (base + 0 < N) starts[base + 0] = excl;
    if (base + 1 < N) starts[base + 1] = excl + v0;
    if (base + 2 < N) starts[base + 2] = excl + v0 + v1;
    if (base + 3 < N) starts[base + 3] = excl + v0 + v1 + v2;
    if (t == 255) bsum[blockIdx.x] = sh[255];
}

__global__ void k_scanB(const int* __restrict__ bsum, int* boff, int nb, int* starts, int N) {
    if (threadIdx.x == 0 && blockIdx.x == 0) {
        int run = 0;
        for (int b = 0; b < nb; ++b) { boff[b] = run; run += bsum[b]; }
        starts[N] = run;
    }
}

__global__ void k_scanC(const int* __restrict__ boff, int* starts, int* cursor, int N) {
    int i = blockIdx.x * 256 + threadIdx.x;
    if (i < N) {
        int v = starts[i] + boff[i >> 10];
        starts[i] = v;
        cursor[i] = v;
    }
}

// ---------------------------------------------------------------------------
// Fused CSR-fill + edge FFN: per edge compute w_bond * relu(ea@E_W + E_b),
// write contiguous 128B row into medge[pos] (CSR slot). No float atomics.
__global__ void k_fill_mij(const float* __restrict__ ea, const int* __restrict__ src,
                           const int* __restrict__ dst, const float* __restrict__ wb,
                           const float* __restrict__ EW, const float* __restrict__ Eb,
                           int* cursor, int* esrc, float* ewS, float* medge, int E) {
    __shared__ float ew_s[EDGEF * EDGEF];
    __shared__ float eb_s[EDGEF];
    int tid = threadIdx.x;
    for (int i = tid; i < EDGEF * EDGEF; i += 256) ew_s[i] = EW[i];
    if (tid < EDGEF) eb_s[tid] = Eb[tid];
    __syncthreads();
    int e = blockIdx.x * 256 + tid;
    if (e >= E) return;
    float a[EDGEF];
    const float4* row = (const float4*)(ea + (size_t)e * EDGEF);
#pragma unroll
    for (int q = 0; q < 8; ++q) {
        float4 v = row[q];
        a[4*q] = v.x; a[4*q+1] = v.y; a[4*q+2] = v.z; a[4*q+3] = v.w;
    }
    float m[EDGEF];
#pragma unroll
    for (int j = 0; j < EDGEF; ++j) m[j] = eb_s[j];
#pragma unroll
    for (int k = 0; k < EDGEF; ++k) {
        float ak = a[k];
#pragma unroll
        for (int j = 0; j < EDGEF; ++j) m[j] = fmaf(ak, ew_s[k*EDGEF + j], m[j]);
    }
    float w = wb[e];
    int pos = atomicAdd(&cursor[dst[e]], 1);
    esrc[pos] = src[e];
    ewS[pos] = w;
    float4* mp = (float4*)(medge + (size_t)pos * EDGEF);
#pragma unroll
    for (int q = 0; q < 8; ++q) {
        float4 v = { w * fmaxf(m[4*q], 0.f),   w * fmaxf(m[4*q+1], 0.f),
                     w * fmaxf(m[4*q+2], 0.f), w * fmaxf(m[4*q+3], 0.f) };
        mp[q] = v;
    }
}

// ---------------------------------------------------------------------------
// aggrE[n] = elu( sum_{edges->n} medge[i] )  -- sequential coalesced reads.
// wave per node; lanes cover 2 edges x 32 channels per iteration.
__global__ __launch_bounds__(256) void k_aggrE(const float* __restrict__ medge,
                                               const int* __restrict__ starts,
                                               float* __restrict__ aggrE_elu, int N) {
    int tid = threadIdx.x;
    int lane = tid & 63, wid = tid >> 6;
    int half = lane >> 5, ch = lane & 31;
    int nwaves = gridDim.x * 4;
    for (int n = blockIdx.x * 4 + wid; n < N; n += nwaves) {
        int s0 = starts[n], s1 = starts[n + 1];
        float acc = 0.f;
        for (int i = s0 + half; i < s1; i += 2)
            acc += medge[(size_t)i * EDGEF + ch];
        acc += __shfl_xor(acc, 32, 64);
        if (lane < EDGEF) aggrE_elu[(size_t)n * EDGEF + lane] = eluf(acc);
    }
}

// ---------------------------------------------------------------------------
// Fused message-passing depth: per-node aggregation (no atomics) + elu + U-FFN
// wave per node. lane j owns channel j. V column j in VGPRs; U^T in LDS.
__global__ __launch_bounds__(256, 3) void k_node(
    const float* __restrict__ h_in, float* __restrict__ h_out,
    const int* __restrict__ starts, const int* __restrict__ esrc,
    const float* __restrict__ ewS, const float* __restrict__ aggrE_elu,
    const float* __restrict__ VW, const float* __restrict__ Vb,
    const float* __restrict__ UW, const float* __restrict__ Ub,
    const float* __restrict__ watoms, int N) {
    __shared__ float lds_Ut[NODE * UT_STRIDE];
    __shared__ float lds_up[4 * UPF];
    int tid = threadIdx.x;
    // stage U^T: Ut[j][t] = U[t*64+j]
    for (int idx = tid; idx < UPF * NODE; idx += 256) {
        int j = idx & 63, t2 = idx >> 6;
        lds_Ut[j * UT_STRIDE + t2] = UW[idx];
    }
    int lane = tid & 63, wid = tid >> 6;
    float vcol[NODE];
#pragma unroll
    for (int k = 0; k < NODE; ++k) vcol[k] = VW[k * NODE + lane];
    float vb = Vb[lane];
    float ub = Ub[lane];
    __syncthreads();
    float* myup = lds_up + wid * UPF;
    int nwaves = gridDim.x * 4;
    for (int n = blockIdx.x * 4 + wid; n < N; n += nwaves) {
        int s0 = starts[n], s1 = starts[n + 1];
        float acc = 0.f;
        int i = s0;
        int sidxN = 0; float ewN = 0.f;
        if (i < s1) { sidxN = esrc[i]; ewN = ewS[i]; }
        for (; i < s1; ++i) {
            int sidx = __builtin_amdgcn_readfirstlane(sidxN);
            float we = ewN;
            if (i + 1 < s1) { sidxN = esrc[i + 1]; ewN = ewS[i + 1]; }
            const float* hp = h_in + (size_t)sidx * NODE;
            // 4 independent chains to hide VALU latency
            float d0 = 0.f, d1 = 0.f, d2 = 0.f, d3 = 0.f;
#pragma unroll
            for (int k = 0; k < NODE; k += 4) {
                d0 = fmaf(hp[k + 0], vcol[k + 0], d0);
                d1 = fmaf(hp[k + 1], vcol[k + 1], d1);
                d2 = fmaf(hp[k + 2], vcol[k + 2], d2);
                d3 = fmaf(hp[k + 3], vcol[k + 3], d3);
            }
            float dot = vb + ((d0 + d1) + (d2 + d3));
            acc = fmaf(we, fmaxf(dot, 0.f), acc);
        }
        // build up = elu([acc(64) | aggrE(32) | h_in[n](64)])
        myup[lane] = eluf(acc);
        if (lane < EDGEF) myup[NODE + lane] = aggrE_elu[(size_t)n * EDGEF + lane];
        myup[NODE + EDGEF + lane] = eluf(h_in[(size_t)n * NODE + lane]);
        // U-FFN: o_j = relu(sum_t up[t]*U[t][j] + Ub_j) * w_atoms[n]
        float o = ub;
#pragma unroll
        for (int t2 = 0; t2 < UPF; t2 += 2) {
            float2 u2 = *(const float2*)&myup[t2];                 // broadcast
            float2 w2 = *(const float2*)&lds_Ut[lane * UT_STRIDE + t2];
            o = fmaf(u2.x, w2.x, o);
            o = fmaf(u2.y, w2.y, o);
        }
        h_out[(size_t)n * NODE + lane] = fmaxf(o, 0.f) * watoms[n];
    }
}

// ---------------------------------------------------------------------------
__global__ void k_add4(const float4* __restrict__ a, const float4* __restrict__ b,
                       float4* __restrict__ o, int n4) {
    int i = blockIdx.x * 256 + threadIdx.x;
    if (i < n4) {
        float4 x = a[i], y = b[i];
        float4 r = { x.x + y.x, x.y + y.y, x.z + y.z, x.w + y.w };
        o[i] = r;
    }
}

// ---------------------------------------------------------------------------
// Readout GEMM y = hx @ R_W + R_b, fused column sum/sumsq for BN
__global__ __launch_bounds__(256, 2) void k_y(
    const float* __restrict__ hx, const float* __restrict__ RW,
    const float* __restrict__ Rb, float* __restrict__ y,
    float* colsum, float* colsumsq, int N) {
    __shared__ float lds_R[NODE * RD];  // 64 KB
    int tid = threadIdx.x;
    for (int i = tid; i < NODE * RD; i += 256) lds_R[i] = RW[i];
    __syncthreads();
    int lane = tid & 63, wid = tid >> 6;
    const float4* R4 = (const float4*)lds_R;
    float4 rb = ((const float4*)Rb)[lane];
    float4 sum = {0, 0, 0, 0}, sq = {0, 0, 0, 0};
    int nwaves = gridDim.x * 4;
    for (int n = blockIdx.x * 4 + wid; n < N; n += nwaves) {
        const float* hr = hx + (size_t)n * NODE;
        float4 acc = rb;
#pragma unroll
        for (int k = 0; k < NODE; ++k) {
            float hk = hr[k];                 // wave-uniform -> scalar load
            float4 r = R4[k * 64 + lane];
            acc.x = fmaf(hk, r.x, acc.x);
            acc.y = fmaf(hk, r.y, acc.y);
            acc.z = fmaf(hk, r.z, acc.z);
            acc.w = fmaf(hk, r.w, acc.w);
        }
        ((float4*)y)[(size_t)n * 64 + lane] = acc;
        sum.x += acc.x; sum.y += acc.y; sum.z += acc.z; sum.w += acc.w;
        sq.x = fmaf(acc.x, acc.x, sq.x); sq.y = fmaf(acc.y, acc.y, sq.y);
        sq.z = fmaf(acc.z, acc.z, sq.z); sq.w = fmaf(acc.w, acc.w, sq.w);
    }
    atomicAdd(&colsum[lane * 4 + 0], sum.x);
    atomicAdd(&colsum[lane * 4 + 1], sum.y);
    atomicAdd(&colsum[lane * 4 + 2], sum.z);
    atomicAdd(&colsum[lane * 4 + 3], sum.w);
    atomicAdd(&colsumsq[lane * 4 + 0], sq.x);
    atomicAdd(&colsumsq[lane * 4 + 1], sq.y);
    atomicAdd(&colsumsq[lane * 4 + 2], sq.z);
    atomicAdd(&colsumsq[lane * 4 + 3], sq.w);
}

// graph boundaries from sorted batch: gstart[g] = first n with batch[n] >= g
__global__ void k_gbounds(const int* __restrict__ batch, int* gstart, int N, int G) {
    int n = blockIdx.x * 256 + threadIdx.x;
    if (n > N) return;
    int bprev = (n == 0) ? -1 : batch[n - 1];
    int bcur = (n == N) ? G : batch[n];
    for (int g = bprev + 1; g <= bcur; ++g) gstart[g] = n;
}

// BN(normalize) + relu + segment mean. block per graph, thread per channel.
__global__ void k_out(const float* __restrict__ y, const float* __restrict__ colsum,
                      const float* __restrict__ colsumsq, const float* __restrict__ gamma,
                      const float* __restrict__ beta, const int* __restrict__ gstart,
                      float* __restrict__ out, float invN) {
    int g = blockIdx.x, c = threadIdx.x;
    float mu = colsum[c] * invN;
    float var = fmaxf(colsumsq[c] * invN - mu * mu, 0.f);
    float inv = rsqrtf(var + 1e-5f);
    float ga = gamma[c], be = beta[c];
    int a = gstart[g], b = gstart[g + 1];
    float acc = 0.f;
    for (int n = a; n < b; ++n) {
        float v = y[(size_t)n * RD + c];
        acc += fmaxf(fmaf((v - mu) * inv, ga, be), 0.f);
    }
    out[(size_t)g * RD + c] = acc / fmaxf((float)(b - a), 1.f);
}

// ---------------------------------------------------------------------------
extern "C" void kernel_launch(void* const* d_in, const int* in_sizes, int n_in,
                              void* d_out, int out_size, void* d_ws, size_t ws_size,
                              hipStream_t stream) {
    const float* x      = (const float*)d_in[0];
    const int*   ei     = (const int*)d_in[1];
    const float* eattr  = (const float*)d_in[2];
    const float* watoms = (const float*)d_in[3];
    const float* wbonds = (const float*)d_in[4];
    const int*   batch  = (const int*)d_in[5];
    const float* VW = (const float*)d_in[6];
    const float* Vb = (const float*)d_in[7];
    const float* EW = (const float*)d_in[8];
    const float* Eb = (const float*)d_in[9];
    const float* UW = (const float*)d_in[10];
    const float* Ub = (const float*)d_in[11];
    const float* RW = (const float*)d_in[12];
    const float* Rb = (const float*)d_in[13];
    const float* Rg = (const float*)d_in[14];
    const float* Rbe = (const float*)d_in[15];
    float* out = (float*)d_out;

    const int N = in_sizes[0] / NODE;
    const int E = in_sizes[4];
    const int G = out_size / RD;
    const int* src = ei;
    const int* dst = ei + E;

    char* p = (char*)d_ws;
    auto alloc = [&](size_t bytes) -> char* {
        char* r = p;
        p += (bytes + 255) & ~(size_t)255;
        return r;
    };
    float* aggrE   = (float*)alloc((size_t)N * EDGEF * 4);   // stores elu(aggrE)
    int*   cnt     = (int*)alloc((size_t)N * 4);
    int*   starts  = (int*)alloc((size_t)(N + 1) * 4);
    int*   cursor  = (int*)alloc((size_t)N * 4);
    int*   bsum    = (int*)alloc(64 * 4);
    int*   boff    = (int*)alloc(64 * 4);
    int*   esrc    = (int*)alloc((size_t)E * 4);
    float* ewS     = (float*)alloc((size_t)E * 4);
    float* hA      = (float*)alloc((size_t)N * NODE * 4);    // h1, later h3
    float* hB      = (float*)alloc((size_t)N * NODE * 4);    // h2, later h4
    float* tmp     = (float*)alloc((size_t)N * NODE * 4);    // sums, later hx
    float* colstat = (float*)alloc((size_t)2 * RD * 4);
    int*   gstart  = (int*)alloc((size_t)(G + 1) * 4);
    // medge (E*32 f32 = 102MB) and ybuf (N*256 f32 = 51MB) have disjoint
    // lifetimes -> overlay.
    size_t big = (size_t)E * EDGEF * 4;
    size_t ybytes = (size_t)N * RD * 4;
    float* medge   = (float*)alloc(big > ybytes ? big : ybytes);
    float* ybuf    = medge;

    hipMemsetAsync(cnt, 0, (size_t)N * 4, stream);
    hipMemsetAsync(colstat, 0, (size_t)2 * RD * 4, stream);

    int eblocks = (E + 255) / 256;
    int sblocks = (N + 1023) / 1024;

    k_count<<<eblocks, 256, 0, stream>>>(dst, cnt, E);
    k_scanA<<<sblocks, 256, 0, stream>>>(cnt, starts, bsum, N);
    k_scanB<<<1, 64, 0, stream>>>(bsum, boff, sblocks, starts, N);
    k_scanC<<<(N + 255) / 256, 256, 0, stream>>>(boff, starts, cursor, N);
    k_fill_mij<<<eblocks, 256, 0, stream>>>(eattr, src, dst, wbonds, EW, Eb,
                                            cursor, esrc, ewS, medge, E);
    k_aggrE<<<1024, 256, 0, stream>>>(medge, starts, aggrE, N);

    int n4 = N * NODE / 4;
    int ablocks = (n4 + 255) / 256;

    // depth 0: h1 = mp(x)
    k_node<<<768, 256, 0, stream>>>(x, hA, starts, esrc, ewS, aggrE, VW, Vb, UW, Ub, watoms, N);
    // depth 1: h2 = mp(h1)
    k_node<<<768, 256, 0, stream>>>(hA, hB, starts, esrc, ewS, aggrE, VW, Vb, UW, Ub, watoms, N);
    // depth 2: h3 = mp(h1 + h2)   (h3 overwrites hA after tmp is formed)
    k_add4<<<ablocks, 256, 0, stream>>>((const float4*)hA, (const float4*)hB, (float4*)tmp, n4);
    k_node<<<768, 256, 0, stream>>>(tmp, hA, starts, esrc, ewS, aggrE, VW, Vb, UW, Ub, watoms, N);
    // depth 3: h4 = mp(h2 + h3)   (h4 overwrites hB)
    k_add4<<<ablocks, 256, 0, stream>>>((const float4*)hB, (const float4*)hA, (float4*)tmp, n4);
    k_node<<<768, 256, 0, stream>>>(tmp, hB, starts, esrc, ewS, aggrE, VW, Vb, UW, Ub, watoms, N);

    // readout: hx = h4 + x (into tmp)
    k_add4<<<ablocks, 256, 0, stream>>>((const float4*)hB, (const float4*)x, (float4*)tmp, n4);
    k_y<<<512, 256, 0, stream>>>(tmp, RW, Rb, ybuf, colstat, colstat + RD, N);
    k_gbounds<<<(N + 256) / 256, 256, 0, stream>>>(batch, gstart, N, G);
    k_out<<<G, RD, 0, stream>>>(ybuf, colstat, colstat + RD, Rg, Rbe, gstart, out, 1.0f / (float)N);
}